// Round 4
// baseline (209.187 us; speedup 1.0000x reference)
//
#include <hip/hip_runtime.h>

#define N_CTX 2048
#define DHEAD 64
#define SCALE_F 0.125f
#define EPS_F 1e-6f
#define KT 64
#define NITER (N_CTX / KT)
#define QBLK 256           // q per block: 4 waves x 64 q-rows

typedef __attribute__((ext_vector_type(8))) short short8;
typedef __attribute__((ext_vector_type(4))) float float4v;
typedef __attribute__((ext_vector_type(2))) unsigned uint2v;
typedef __attribute__((ext_vector_type(4))) unsigned uint4v;

// ---- bf16 pack: HW cvt_pk on device, parse-only fallback for host pass ----
#if defined(__HIP_DEVICE_COMPILE__) && __has_builtin(__builtin_amdgcn_cvt_pk_bf16_f32)
typedef __attribute__((ext_vector_type(2))) __bf16 bf16x2;
__device__ __forceinline__ unsigned pack2(float a, float b) {
    union { bf16x2 v; unsigned u; } x;
    x.v = __builtin_amdgcn_cvt_pk_bf16_f32(a, b);
    return x.u;
}
#else
__device__ __forceinline__ unsigned bf1(float f) {
    union { float f; unsigned u; } x; x.f = f;
    return (x.u + 0x7FFFu + ((x.u >> 16) & 1u)) >> 16;
}
__device__ __forceinline__ unsigned pack2(float a, float b) {
    return bf1(a) | (bf1(b) << 16);
}
#endif

// ---- gfx950 permlane swaps (K=16 C-layout -> K=32 A-frag re-tile) ----
#if defined(__HIP_DEVICE_COMPILE__) && __has_builtin(__builtin_amdgcn_permlane32_swap)
__device__ __forceinline__ void pl32(unsigned &x, unsigned &y) {
    uint2v r = __builtin_amdgcn_permlane32_swap(x, y, false, false);
    x = r[0]; y = r[1];
}
#else
__device__ __forceinline__ void pl32(unsigned &x, unsigned &y) {
    asm volatile("v_permlane32_swap_b32 %0, %1" : "+v"(x), "+v"(y));
}
#endif
#if defined(__HIP_DEVICE_COMPILE__) && __has_builtin(__builtin_amdgcn_permlane16_swap)
__device__ __forceinline__ void pl16(unsigned &x, unsigned &y) {
    uint2v r = __builtin_amdgcn_permlane16_swap(x, y, false, false);
    x = r[0]; y = r[1];
}
#else
__device__ __forceinline__ void pl16(unsigned &x, unsigned &y) {
    asm volatile("v_permlane16_swap_b32 %0, %1" : "+v"(x), "+v"(y));
}
#endif

// ---- LDS XOR swizzle (T2 / G4): unpadded [64][64] bf16 tiles (128B rows).
// A short at logical (row, col) lives at physical col ^ ((row&7)<<3).
// Swizzle bits are >=3, so 4-short (b64) and 8-short (b128) aligned runs
// stay contiguous. All fragment reads use row&7 == c&7, so each 8-lane
// phase group's 16B segments tile all 32 banks -> conflict-free b128 reads.
__device__ __forceinline__ int swz(int row, int col) {
    return col ^ ((row & 7) << 3);
}

// Layouts (gfx950, m89-verified):
//  mfma 16x16x32: A[m=lane&15][k=8q+j], B[k=8q+j][n=lane&15], C[row=4q+r][col=lane&15]
// S^T = K*Q^T (M=kv,N=q,K=d): lane(c,qd) holds S^T[kv=16mt+4qd+r][q=c].
// Square in regs -> permlane re-tile -> K=32 PV; O's C layout matches the
// old K=16 path, so epilogue is unchanged.
//
// R4 vs R3(115.5us): (1) unpadded tiles + XOR swizzle on both LDS sides
// (kills the 8-way b128 read conflicts R3 introduced: 11.5M -> pred <5M);
// (2) s_setprio(1) around MFMA clusters (2 independent blocks/CU = the
// regime where T5 measured +4-7%).

__global__ __launch_bounds__(256, 2)
void powsm_attn(const float* __restrict__ qg, const float* __restrict__ kg,
                const float* __restrict__ vg, float* __restrict__ og)
{
    __shared__ __align__(16) short KsB[2][64][64];  // K tile row-major bf16, swizzled
    __shared__ __align__(16) short VtB[2][64][64];  // V^T tile Vt[d][kv], swizzled
    __shared__ float Dn[4][64];                     // denominator exchange

    const int bh   = blockIdx.y;
    const int tid  = threadIdx.x;
    const int wave = tid >> 6;
    const int lane = tid & 63;
    const int qd   = lane >> 4;    // quad 0..3
    const int c    = lane & 15;

    const size_t base = (size_t)bh * N_CTX * DHEAD;
    const float* qp = qg + base;
    const float* kp = kg + base;
    const float* vp = vg + base;
    float*       op = og + base;

    const int qw0 = blockIdx.x * QBLK + wave * 64;

    // ---- hoist Q B-frags (16x16x32), SCALE folded in ----
    short8 Qf[4][2];
    #pragma unroll
    for (int qt = 0; qt < 4; ++qt) {
        #pragma unroll
        for (int ks = 0; ks < 2; ++ks) {
            const float* src = qp + (size_t)(qw0 + qt*16 + c) * DHEAD + ks*32 + qd*8;
            float4v a = *(const float4v*)(src);
            float4v b = *(const float4v*)(src + 4);
            uint4v u;
            u[0] = pack2(a[0]*SCALE_F, a[1]*SCALE_F);
            u[1] = pack2(a[2]*SCALE_F, a[3]*SCALE_F);
            u[2] = pack2(b[0]*SCALE_F, b[1]*SCALE_F);
            u[3] = pack2(b[2]*SCALE_F, b[3]*SCALE_F);
            union { uint4v u; short8 s; } cv; cv.u = u;
            Qf[qt][ks] = cv.s;
        }
    }

    float4v Oacc[4][4];            // [qt][nt]
    #pragma unroll
    for (int qt = 0; qt < 4; ++qt)
        #pragma unroll
        for (int nt = 0; nt < 4; ++nt)
            Oacc[qt][nt] = (float4v){0.f, 0.f, 0.f, 0.f};
    float4v dacc[4];
    #pragma unroll
    for (int qt = 0; qt < 4; ++qt) dacc[qt] = (float4v){0.f, 0.f, 0.f, 0.f};

    const int kr = tid >> 4;       // K-stage row (+u*16), V 4-row group
    const int kc = tid & 15;       // col group

    // ---- load tile 0 + prologue stage into buf0 ----
    float4v pK[4], pV[4];
    #pragma unroll
    for (int u = 0; u < 4; ++u)
        pK[u] = *(const float4v*)(kp + (size_t)(kr + u*16) * DHEAD + kc*4);
    #pragma unroll
    for (int j = 0; j < 4; ++j)
        pV[j] = *(const float4v*)(vp + (size_t)(4*kr + j) * DHEAD + kc*4);

    {
        short (*Ks)[64] = KsB[0];
        short (*Vt)[64] = VtB[0];
        #pragma unroll
        for (int u = 0; u < 4; ++u) {
            const int row = kr + u*16;
            uint2v w; w[0] = pack2(pK[u][0], pK[u][1]); w[1] = pack2(pK[u][2], pK[u][3]);
            *(uint2v*)&Ks[row][swz(row, kc*4)] = w;
        }
        #pragma unroll
        for (int kk = 0; kk < 4; ++kk) {
            const int row = 4*kc + kk;
            uint2v w; w[0] = pack2(pV[0][kk], pV[1][kk]); w[1] = pack2(pV[2][kk], pV[3][kk]);
            *(uint2v*)&Vt[row][swz(row, 4*kr)] = w;
        }
    }
    __syncthreads();

    #pragma unroll 1
    for (int kvi = 0; kvi < NITER; ++kvi) {
        const int cur = kvi & 1;
        short (*Ks)[64] = KsB[cur];
        short (*Vt)[64] = VtB[cur];

        // ---- issue next-tile loads early (land during compute) ----
        if (kvi + 1 < NITER) {
            const float* kn = kp + (size_t)(kvi + 1) * KT * DHEAD;
            const float* vn = vp + (size_t)(kvi + 1) * KT * DHEAD;
            #pragma unroll
            for (int u = 0; u < 4; ++u)
                pK[u] = *(const float4v*)(kn + (size_t)(kr + u*16) * DHEAD + kc*4);
            #pragma unroll
            for (int j = 0; j < 4; ++j)
                pV[j] = *(const float4v*)(vn + (size_t)(4*kr + j) * DHEAD + kc*4);
        }

        // ---- compute: per 32-kv block ----
        #pragma unroll
        for (int blk = 0; blk < 2; ++blk) {
            float4v slo[4], shi[4];
            #pragma unroll
            for (int qt = 0; qt < 4; ++qt) {
                slo[qt] = (float4v){0.f, 0.f, 0.f, 0.f};
                shi[qt] = (float4v){0.f, 0.f, 0.f, 0.f};
            }
            __builtin_amdgcn_s_setprio(1);
            #pragma unroll
            for (int ks = 0; ks < 2; ++ks) {
                short8 afl = *(const short8*)&Ks[blk*32 + c][swz(c, ks*32 + qd*8)];
                #pragma unroll
                for (int qt = 0; qt < 4; ++qt)
                    slo[qt] = __builtin_amdgcn_mfma_f32_16x16x32_bf16(afl, Qf[qt][ks], slo[qt], 0, 0, 0);
            }
            #pragma unroll
            for (int ks = 0; ks < 2; ++ks) {
                short8 afh = *(const short8*)&Ks[blk*32 + 16 + c][swz(c, ks*32 + qd*8)];
                #pragma unroll
                for (int qt = 0; qt < 4; ++qt)
                    shi[qt] = __builtin_amdgcn_mfma_f32_16x16x32_bf16(afh, Qf[qt][ks], shi[qt], 0, 0, 0);
            }
            __builtin_amdgcn_s_setprio(0);
            // square + denom + pack + K32 re-tile (4 permlanes per qt)
            short8 pa[4];
            #pragma unroll
            for (int qt = 0; qt < 4; ++qt) {
                float l0 = slo[qt][0]*slo[qt][0], l1 = slo[qt][1]*slo[qt][1];
                float l2 = slo[qt][2]*slo[qt][2], l3 = slo[qt][3]*slo[qt][3];
                float h0 = shi[qt][0]*shi[qt][0], h1 = shi[qt][1]*shi[qt][1];
                float h2 = shi[qt][2]*shi[qt][2], h3 = shi[qt][3]*shi[qt][3];
                dacc[qt][0] += l0 + h0; dacc[qt][1] += l1 + h1;
                dacc[qt][2] += l2 + h2; dacc[qt][3] += l3 + h3;
                unsigned w00 = pack2(l0, l1);   // (h=0,u=0)
                unsigned w01 = pack2(l2, l3);   // (h=0,u=1)
                unsigned w10 = pack2(h0, h1);   // (h=1,u=0)
                unsigned w11 = pack2(h2, h3);   // (h=1,u=1)
                pl32(w00, w10);                 // lane-bit5 <-> h
                pl32(w01, w11);
                pl16(w00, w10);                 // lane-bit4 <-> g_hi
                pl16(w01, w11);
                union { uint4v u; short8 s; } cv;
                cv.u[0] = w00; cv.u[1] = w01; cv.u[2] = w10; cv.u[3] = w11;
                pa[qt] = cv.s;
            }
            // PV at K=32
            __builtin_amdgcn_s_setprio(1);
            #pragma unroll
            for (int nt = 0; nt < 4; ++nt) {
                short8 bf = *(const short8*)&Vt[nt*16 + c][swz(c, blk*32 + qd*8)];
                #pragma unroll
                for (int qt = 0; qt < 4; ++qt)
                    Oacc[qt][nt] = __builtin_amdgcn_mfma_f32_16x16x32_bf16(pa[qt], bf, Oacc[qt][nt], 0, 0, 0);
            }
            __builtin_amdgcn_s_setprio(0);
        }

        // ---- stage next tile into the other buffer (after compute) ----
        if (kvi + 1 < NITER) {
            short (*Kn)[64] = KsB[cur ^ 1];
            short (*Vn)[64] = VtB[cur ^ 1];
            #pragma unroll
            for (int u = 0; u < 4; ++u) {
                const int row = kr + u*16;
                uint2v w; w[0] = pack2(pK[u][0], pK[u][1]); w[1] = pack2(pK[u][2], pK[u][3]);
                *(uint2v*)&Kn[row][swz(row, kc*4)] = w;
            }
            #pragma unroll
            for (int kk = 0; kk < 4; ++kk) {
                const int row = 4*kc + kk;
                uint2v w; w[0] = pack2(pV[0][kk], pV[1][kk]); w[1] = pack2(pV[2][kk], pV[3][kk]);
                *(uint2v*)&Vn[row][swz(row, 4*kr)] = w;
            }
        }
        __syncthreads();
    }

    // ---- denominator: full sum per q via cross-quad reduce ----
    #pragma unroll
    for (int qt = 0; qt < 4; ++qt) {
        float d = (dacc[qt][0] + dacc[qt][1]) + (dacc[qt][2] + dacc[qt][3]);
        d += __shfl_xor(d, 16);
        d += __shfl_xor(d, 32);
        if (qd == 0) Dn[wave][qt*16 + c] = d;
    }
    __syncthreads();

    // ---- epilogue ----
    #pragma unroll
    for (int qt = 0; qt < 4; ++qt) {
        #pragma unroll
        for (int r = 0; r < 4; ++r) {
            float inv = 1.0f / (Dn[wave][qt*16 + qd*4 + r] + EPS_F);
            float* dst = op + (size_t)(qw0 + qt*16 + qd*4 + r) * DHEAD + c;
            #pragma unroll
            for (int nt = 0; nt < 4; ++nt)
                dst[nt*16] = Oacc[qt][nt][r] * inv;
        }
    }
}

extern "C" void kernel_launch(void* const* d_in, const int* in_sizes, int n_in,
                              void* d_out, int out_size, void* d_ws, size_t ws_size,
                              hipStream_t stream) {
    const float* q = (const float*)d_in[0];
    const float* k = (const float*)d_in[1];
    const float* v = (const float*)d_in[2];
    float* out = (float*)d_out;
    dim3 grid(N_CTX / QBLK, 64, 1);   // (8 q-tiles, B*H) = 512 blocks = 2/CU
    powsm_attn<<<grid, dim3(256, 1, 1), 0, stream>>>(q, k, v, out);
}

// Round 5
// 200.595 us; speedup vs baseline: 1.0428x; 1.0428x over previous
//
#include <hip/hip_runtime.h>

#define N_CTX 2048
#define DHEAD 64
#define SCALE_F 0.125f
#define EPS_F 1e-6f
#define KT 64
#define NITER (N_CTX / KT)
#define QBLK 256           // q per block: 4 waves x 64 q-rows

typedef __attribute__((ext_vector_type(8))) short short8;
typedef __attribute__((ext_vector_type(4))) float float4v;
typedef __attribute__((ext_vector_type(2))) unsigned uint2v;
typedef __attribute__((ext_vector_type(4))) unsigned uint4v;

// ---- bf16 pack: HW cvt_pk on device, parse-only fallback for host pass ----
#if defined(__HIP_DEVICE_COMPILE__) && __has_builtin(__builtin_amdgcn_cvt_pk_bf16_f32)
typedef __attribute__((ext_vector_type(2))) __bf16 bf16x2;
__device__ __forceinline__ unsigned pack2(float a, float b) {
    union { bf16x2 v; unsigned u; } x;
    x.v = __builtin_amdgcn_cvt_pk_bf16_f32(a, b);
    return x.u;
}
#else
__device__ __forceinline__ unsigned bf1(float f) {
    union { float f; unsigned u; } x; x.f = f;
    return (x.u + 0x7FFFu + ((x.u >> 16) & 1u)) >> 16;
}
__device__ __forceinline__ unsigned pack2(float a, float b) {
    return bf1(a) | (bf1(b) << 16);
}
#endif

// ---- gfx950 permlane swaps (K=16 C-layout -> K=32 A-frag re-tile) ----
#if defined(__HIP_DEVICE_COMPILE__) && __has_builtin(__builtin_amdgcn_permlane32_swap)
__device__ __forceinline__ void pl32(unsigned &x, unsigned &y) {
    uint2v r = __builtin_amdgcn_permlane32_swap(x, y, false, false);
    x = r[0]; y = r[1];
}
#else
__device__ __forceinline__ void pl32(unsigned &x, unsigned &y) {
    asm volatile("v_permlane32_swap_b32 %0, %1" : "+v"(x), "+v"(y));
}
#endif
#if defined(__HIP_DEVICE_COMPILE__) && __has_builtin(__builtin_amdgcn_permlane16_swap)
__device__ __forceinline__ void pl16(unsigned &x, unsigned &y) {
    uint2v r = __builtin_amdgcn_permlane16_swap(x, y, false, false);
    x = r[0]; y = r[1];
}
#else
__device__ __forceinline__ void pl16(unsigned &x, unsigned &y) {
    asm volatile("v_permlane16_swap_b32 %0, %1" : "+v"(x), "+v"(y));
}
#endif

// ---- LDS XOR swizzle (T2 / G4): unpadded [64][64] bf16 tiles (128B rows).
// short at logical (row,col) lives at physical col ^ ((row&7)<<3). Swizzle
// bits >=3 keep 4/8-short aligned runs contiguous; frag reads have
// row&7 == c&7 so each 8-lane group's 16B segments tile all 32 banks.
__device__ __forceinline__ int swz(int row, int col) {
    return col ^ ((row & 7) << 3);
}

// Layouts (gfx950, m89-verified):
//  mfma 16x16x32: A[m=lane&15][k=8q+j], B[k=8q+j][n=lane&15], C[row=4q+r][col=lane&15]
// S^T = K*Q^T (M=kv,N=q,K=d): lane(c,qd) holds S^T[kv=16mt+4qd+r][q=c].
// Square in regs -> permlane re-tile -> K=32 PV; O's C layout matches the
// epilogue write.
//
// R5 vs R4(127.4us regression): (1) REVERT setprio (priority inversion with
// 2 lockstep waves/SIMD = the m190 null/negative regime; R4's +12us stall);
// (2) keep XOR swizzle (conflicts 11.5M->7.3M, mechanism sound);
// (3) denominator via ones-column MFMA: bfden is a register constant
//     (B[k][n]=1 iff n==0), Oden = P*1 accumulates Σ P in col 0 of a C-frag.
//     Deletes 64 v_add/iter (dacc) + epilogue shfl chain; +8 MFMA/iter.
// (4) squares as float4v vector mul (enables v_pk_mul_f32).

__global__ __launch_bounds__(256, 2)
void powsm_attn(const float* __restrict__ qg, const float* __restrict__ kg,
                const float* __restrict__ vg, float* __restrict__ og)
{
    __shared__ __align__(16) short KsB[2][64][64];  // K tile row-major bf16, swizzled
    __shared__ __align__(16) short VtB[2][64][64];  // V^T tile Vt[d][kv], swizzled
    __shared__ float Dn[4][64];                     // denominator exchange

    const int bh   = blockIdx.y;
    const int tid  = threadIdx.x;
    const int wave = tid >> 6;
    const int lane = tid & 63;
    const int qd   = lane >> 4;    // quad 0..3
    const int c    = lane & 15;

    const size_t base = (size_t)bh * N_CTX * DHEAD;
    const float* qp = qg + base;
    const float* kp = kg + base;
    const float* vp = vg + base;
    float*       op = og + base;

    const int qw0 = blockIdx.x * QBLK + wave * 64;

    // ---- denominator B-frag: B[k][n=c] = (c==0) ? 1.0bf16 : 0, any k ----
    union { uint4v u; short8 s; } dvu;
    {
        const unsigned ob = (c == 0) ? 0x3F803F80u : 0u;
        dvu.u[0] = ob; dvu.u[1] = ob; dvu.u[2] = ob; dvu.u[3] = ob;
    }
    const short8 bfden = dvu.s;

    // ---- hoist Q B-frags (16x16x32), SCALE folded in ----
    short8 Qf[4][2];
    #pragma unroll
    for (int qt = 0; qt < 4; ++qt) {
        #pragma unroll
        for (int ks = 0; ks < 2; ++ks) {
            const float* src = qp + (size_t)(qw0 + qt*16 + c) * DHEAD + ks*32 + qd*8;
            float4v a = *(const float4v*)(src);
            float4v b = *(const float4v*)(src + 4);
            uint4v u;
            u[0] = pack2(a[0]*SCALE_F, a[1]*SCALE_F);
            u[1] = pack2(a[2]*SCALE_F, a[3]*SCALE_F);
            u[2] = pack2(b[0]*SCALE_F, b[1]*SCALE_F);
            u[3] = pack2(b[2]*SCALE_F, b[3]*SCALE_F);
            union { uint4v u; short8 s; } cv; cv.u = u;
            Qf[qt][ks] = cv.s;
        }
    }

    float4v Oacc[4][4];            // [qt][nt]
    #pragma unroll
    for (int qt = 0; qt < 4; ++qt)
        #pragma unroll
        for (int nt = 0; nt < 4; ++nt)
            Oacc[qt][nt] = (float4v){0.f, 0.f, 0.f, 0.f};
    float4v Oden[4];               // denominator C-frag (col 0 = Σ P)
    #pragma unroll
    for (int qt = 0; qt < 4; ++qt) Oden[qt] = (float4v){0.f, 0.f, 0.f, 0.f};

    const int kr = tid >> 4;       // K-stage row (+u*16), V 4-row group
    const int kc = tid & 15;       // col group

    // ---- load tile 0 + prologue stage into buf0 ----
    float4v pK[4], pV[4];
    #pragma unroll
    for (int u = 0; u < 4; ++u)
        pK[u] = *(const float4v*)(kp + (size_t)(kr + u*16) * DHEAD + kc*4);
    #pragma unroll
    for (int j = 0; j < 4; ++j)
        pV[j] = *(const float4v*)(vp + (size_t)(4*kr + j) * DHEAD + kc*4);

    {
        short (*Ks)[64] = KsB[0];
        short (*Vt)[64] = VtB[0];
        #pragma unroll
        for (int u = 0; u < 4; ++u) {
            const int row = kr + u*16;
            uint2v w; w[0] = pack2(pK[u][0], pK[u][1]); w[1] = pack2(pK[u][2], pK[u][3]);
            *(uint2v*)&Ks[row][swz(row, kc*4)] = w;
        }
        #pragma unroll
        for (int kk = 0; kk < 4; ++kk) {
            const int row = 4*kc + kk;
            uint2v w; w[0] = pack2(pV[0][kk], pV[1][kk]); w[1] = pack2(pV[2][kk], pV[3][kk]);
            *(uint2v*)&Vt[row][swz(row, 4*kr)] = w;
        }
    }
    __syncthreads();

    #pragma unroll 1
    for (int kvi = 0; kvi < NITER; ++kvi) {
        const int cur = kvi & 1;
        short (*Ks)[64] = KsB[cur];
        short (*Vt)[64] = VtB[cur];

        // ---- issue next-tile loads early (land during compute) ----
        if (kvi + 1 < NITER) {
            const float* kn = kp + (size_t)(kvi + 1) * KT * DHEAD;
            const float* vn = vp + (size_t)(kvi + 1) * KT * DHEAD;
            #pragma unroll
            for (int u = 0; u < 4; ++u)
                pK[u] = *(const float4v*)(kn + (size_t)(kr + u*16) * DHEAD + kc*4);
            #pragma unroll
            for (int j = 0; j < 4; ++j)
                pV[j] = *(const float4v*)(vn + (size_t)(4*kr + j) * DHEAD + kc*4);
        }

        // ---- compute: per 32-kv block ----
        #pragma unroll
        for (int blk = 0; blk < 2; ++blk) {
            float4v slo[4], shi[4];
            #pragma unroll
            for (int qt = 0; qt < 4; ++qt) {
                slo[qt] = (float4v){0.f, 0.f, 0.f, 0.f};
                shi[qt] = (float4v){0.f, 0.f, 0.f, 0.f};
            }
            #pragma unroll
            for (int ks = 0; ks < 2; ++ks) {
                short8 afl = *(const short8*)&Ks[blk*32 + c][swz(c, ks*32 + qd*8)];
                #pragma unroll
                for (int qt = 0; qt < 4; ++qt)
                    slo[qt] = __builtin_amdgcn_mfma_f32_16x16x32_bf16(afl, Qf[qt][ks], slo[qt], 0, 0, 0);
            }
            #pragma unroll
            for (int ks = 0; ks < 2; ++ks) {
                short8 afh = *(const short8*)&Ks[blk*32 + 16 + c][swz(c, ks*32 + qd*8)];
                #pragma unroll
                for (int qt = 0; qt < 4; ++qt)
                    shi[qt] = __builtin_amdgcn_mfma_f32_16x16x32_bf16(afh, Qf[qt][ks], shi[qt], 0, 0, 0);
            }
            // square (vectorized) + pack + K32 re-tile (4 permlanes per qt)
            short8 pa[4];
            #pragma unroll
            for (int qt = 0; qt < 4; ++qt) {
                float4v psl = slo[qt] * slo[qt];
                float4v psh = shi[qt] * shi[qt];
                unsigned w00 = pack2(psl[0], psl[1]);   // (h=0,u=0)
                unsigned w01 = pack2(psl[2], psl[3]);   // (h=0,u=1)
                unsigned w10 = pack2(psh[0], psh[1]);   // (h=1,u=0)
                unsigned w11 = pack2(psh[2], psh[3]);   // (h=1,u=1)
                pl32(w00, w10);                 // lane-bit5 <-> h
                pl32(w01, w11);
                pl16(w00, w10);                 // lane-bit4 <-> g_hi
                pl16(w01, w11);
                union { uint4v u; short8 s; } cv;
                cv.u[0] = w00; cv.u[1] = w01; cv.u[2] = w10; cv.u[3] = w11;
                pa[qt] = cv.s;
            }
            // denominator: Σ P into col 0 (register-constant B operand)
            #pragma unroll
            for (int qt = 0; qt < 4; ++qt)
                Oden[qt] = __builtin_amdgcn_mfma_f32_16x16x32_bf16(pa[qt], bfden, Oden[qt], 0, 0, 0);
            // PV at K=32
            #pragma unroll
            for (int nt = 0; nt < 4; ++nt) {
                short8 bf = *(const short8*)&Vt[nt*16 + c][swz(c, blk*32 + qd*8)];
                #pragma unroll
                for (int qt = 0; qt < 4; ++qt)
                    Oacc[qt][nt] = __builtin_amdgcn_mfma_f32_16x16x32_bf16(pa[qt], bf, Oacc[qt][nt], 0, 0, 0);
            }
        }

        // ---- stage next tile into the other buffer (after compute) ----
        if (kvi + 1 < NITER) {
            short (*Kn)[64] = KsB[cur ^ 1];
            short (*Vn)[64] = VtB[cur ^ 1];
            #pragma unroll
            for (int u = 0; u < 4; ++u) {
                const int row = kr + u*16;
                uint2v w; w[0] = pack2(pK[u][0], pK[u][1]); w[1] = pack2(pK[u][2], pK[u][3]);
                *(uint2v*)&Kn[row][swz(row, kc*4)] = w;
            }
            #pragma unroll
            for (int kk = 0; kk < 4; ++kk) {
                const int row = 4*kc + kk;
                uint2v w; w[0] = pack2(pV[0][kk], pV[1][kk]); w[1] = pack2(pV[2][kk], pV[3][kk]);
                *(uint2v*)&Vn[row][swz(row, 4*kr)] = w;
            }
        }
        __syncthreads();
    }

    // ---- denominator exchange: lanes c==0 hold col 0 of the C-frag ----
    if (c == 0) {
        #pragma unroll
        for (int qt = 0; qt < 4; ++qt)
            #pragma unroll
            for (int r = 0; r < 4; ++r)
                Dn[wave][qt*16 + qd*4 + r] = Oden[qt][r];
    }
    __syncthreads();

    // ---- epilogue ----
    #pragma unroll
    for (int qt = 0; qt < 4; ++qt) {
        #pragma unroll
        for (int r = 0; r < 4; ++r) {
            float inv = 1.0f / (Dn[wave][qt*16 + qd*4 + r] + EPS_F);
            float* dst = op + (size_t)(qw0 + qt*16 + qd*4 + r) * DHEAD + c;
            #pragma unroll
            for (int nt = 0; nt < 4; ++nt)
                dst[nt*16] = Oacc[qt][nt][r] * inv;
        }
    }
}

extern "C" void kernel_launch(void* const* d_in, const int* in_sizes, int n_in,
                              void* d_out, int out_size, void* d_ws, size_t ws_size,
                              hipStream_t stream) {
    const float* q = (const float*)d_in[0];
    const float* k = (const float*)d_in[1];
    const float* v = (const float*)d_in[2];
    float* out = (float*)d_out;
    dim3 grid(N_CTX / QBLK, 64, 1);   // (8 q-tiles, B*H) = 512 blocks = 2/CU
    powsm_attn<<<grid, dim3(256, 1, 1), 0, stream>>>(q, k, v, out);
}